// Round 8
// baseline (286.202 us; speedup 1.0000x reference)
//
#include <hip/hip_runtime.h>

static constexpr int Tn = 2000;
static constexpr int Bn = 512;
static constexpr int Cn = 29;
static constexpr int Ln = 150;
static constexpr float LOG2E_F = 1.4426950408889634f;
static constexpr float LN2_F   = 0.6931471805599453f;
static constexpr float NEGV    = -1e30f;

// workspace layout (floats)
static constexpr int WS_DEN_F = 0;                      // 512 (log2-domain log_den per b)
static constexpr int WS_NUM_F = 2 * 512 * 32;           // 512*160
static constexpr int WS_NUM_B = 2 * 512 * 32 + 512 * 160;

static constexpr int NSEG = 8;                          // den segments per batch
static constexpr int SEGL = 250;                        // steps per segment (last: 249)

typedef float  f32x16 __attribute__((ext_vector_type(16)));
typedef float  f32x4  __attribute__((ext_vector_type(4)));
typedef __bf16 bf16x8 __attribute__((ext_vector_type(8)));
typedef unsigned int u32x4 __attribute__((ext_vector_type(4)));

#if __has_builtin(__builtin_amdgcn_exp2f)
#define FEXP2(x) __builtin_amdgcn_exp2f(x)
#else
#define FEXP2(x) exp2f(x)
#endif
#if __has_builtin(__builtin_amdgcn_logf)
#define FLOG2(x) __builtin_amdgcn_logf(x)
#else
#define FLOG2(x) log2f(x)
#endif

__device__ __forceinline__ float ladd2(float x, float y) {
    float m = fmaxf(x, y);
    float d = fminf(x, y) - m;
    return m + FLOG2(1.0f + FEXP2(d));
}
__device__ __forceinline__ int exp_of(float x) {           // floor(log2(x)), x normal >0
    return ((__float_as_int(x) >> 23) & 255) - 127;
}
__device__ __forceinline__ float pow2i(int e) {            // 2^e, e in [-126,127]
    return __int_as_float((e + 127) << 23);
}
__device__ __forceinline__ unsigned short f2bf_rne(float x) {
    unsigned u = __float_as_uint(x);
    u += 0x7fffu + ((u >> 16) & 1u);
    return (unsigned short)(u >> 16);
}
__device__ __forceinline__ unsigned cvtpk_bf16(float lo, float hi) {
    unsigned r;
    asm("v_cvt_pk_bf16_f32 %0, %1, %2" : "=v"(r) : "v"(lo), "v"(hi));
    return r;
}
__device__ __forceinline__ void xswap32(unsigned &a, unsigned &b) {
#if __has_builtin(__builtin_amdgcn_permlane32_swap)
    auto r = __builtin_amdgcn_permlane32_swap(a, b, false, false);
    a = r[0]; b = r[1];
#else
    unsigned pa = (unsigned)__shfl_xor((int)a, 32);
    unsigned pb = (unsigned)__shfl_xor((int)b, 32);
    bool hb = (threadIdx.x & 32) != 0;
    unsigned na = hb ? pb : a;
    unsigned nb = hb ? b : pa;
    a = na; b = nb;
#endif
}
// D-layout f32[16] -> B-operand fragments (validated r4-r6)
__device__ __forceinline__ void packDtoB(const float* W, bf16x8 &B1, bf16x8 &B2) {
    unsigned pk[8];
#pragma unroll
    for (int q = 0; q < 8; ++q) pk[q] = cvtpk_bf16(W[2 * q], W[2 * q + 1]);
    xswap32(pk[0], pk[2]); xswap32(pk[1], pk[3]);
    xswap32(pk[4], pk[6]); xswap32(pk[5], pk[7]);
    B1 = __builtin_bit_cast(bf16x8, u32x4{pk[0], pk[1], pk[2], pk[3]});
    B2 = __builtin_bit_cast(bf16x8, u32x4{pk[4], pk[5], pk[6], pk[7]});
}
__device__ __forceinline__ void renorm16(float* W, float &Sacc) {
    float m = W[0];
#pragma unroll
    for (int r = 1; r < 16; ++r) m = fmaxf(m, W[r]);
#pragma unroll
    for (int sh = 1; sh <= 32; sh <<= 1) m = fmaxf(m, __shfl_xor(m, sh));
    int g = exp_of(m);
    float iv = pow2i(-g);
#pragma unroll
    for (int r = 0; r < 16; ++r) W[r] *= iv;
    Sacc += (float)g;
}

__global__ __launch_bounds__(512)
void asg_scan(const float* __restrict__ inp, const float* __restrict__ tr,
              const int* __restrict__ tg, float* __restrict__ ws)
{
    const int tid = threadIdx.x;
    const int bid = blockIdx.x;

    __shared__ float mats[NSEG][32][33];
    __shared__ float uring[NSEG][8][32];
    __shared__ float scl[NSEG];

    if (bid >= 128) {
        // ============ DENOMINATOR: 8 segment transfer matrices / batch =======
        const int lane = tid & 63;
        const int wid  = tid >> 6;           // 0..7 = segment
        const int col  = lane & 31;
        const int hi   = lane >> 5;
        const int b    = bid - 128;
        const size_t BC = (size_t)Bn * Cn;

        // E in bf16 A-fragments (validated r4)
        unsigned aw[8];
#pragma unroll
        for (int p = 0; p < 8; ++p) {
            int kb = (p >> 2) * 16 + 8 * hi + (p & 3) * 2;
            unsigned short lo = 0, hh = 0;
            if (col < Cn) {
                if (kb < Cn)     lo = f2bf_rne(FEXP2(LOG2E_F * tr[(1 + col) * Cn + kb]));
                if (kb + 1 < Cn) hh = f2bf_rne(FEXP2(LOG2E_F * tr[(1 + col) * Cn + kb + 1]));
            }
            aw[p] = (unsigned)lo | ((unsigned)hh << 16);
        }
        const bf16x8 A1 = __builtin_bit_cast(bf16x8, u32x4{aw[0], aw[1], aw[2], aw[3]});
        const bf16x8 A2 = __builtin_bit_cast(bf16x8, u32x4{aw[4], aw[5], aw[6], aw[7]});

        f32x16 z;
#pragma unroll
        for (int r = 0; r < 16; ++r) z[r] = 0.f;

        const int start = 1 + SEGL * wid;
        const int cnt   = min(SEGL, Tn - start);           // 250 ... 249

        const float* ebase = inp + (size_t)b * Cn + min(col, Cn - 1);

        float er[8];
#pragma unroll
        for (int p = 0; p < 8; ++p)
            er[p] = ebase[(size_t)min(start + p, Tn - 1) * BC];

        if (lane < 32) {
            uring[wid][0][col] = FEXP2(LOG2E_F * er[0]);
            uring[wid][1][col] = FEXP2(LOG2E_F * er[1]);
        }

        float W[16];                                       // M in D-layout, init I
#pragma unroll
        for (int r = 0; r < 16; ++r) {
            int row = (r & 3) + 8 * (r >> 2) + 4 * hi;
            W[r] = (row == col) ? 1.0f : 0.0f;
        }
        float Sacc = 0.f;

        int s = 0;
        for (; s + 8 <= cnt; s += 8) {
#pragma unroll
            for (int u = 0; u < 8; ++u) {
                er[u] = ebase[(size_t)min(start + s + u + 8, Tn - 1) * BC];  // prefetch
                float un = FEXP2(LOG2E_F * er[(u + 2) & 7]);                 // step s+u+2
                if (lane < 32) uring[wid][(u + 2) & 7][col] = un;
                f32x4 uu0 = *(const f32x4*)&uring[wid][u][4 * hi];
                f32x4 uu1 = *(const f32x4*)&uring[wid][u][8 + 4 * hi];
                f32x4 uu2 = *(const f32x4*)&uring[wid][u][16 + 4 * hi];
                f32x4 uu3 = *(const f32x4*)&uring[wid][u][24 + 4 * hi];
                bf16x8 B1, B2;
                packDtoB(W, B1, B2);
                f32x16 d = __builtin_amdgcn_mfma_f32_32x32x16_bf16(A1, B1, z, 0, 0, 0);
                d = __builtin_amdgcn_mfma_f32_32x32x16_bf16(A2, B2, d, 0, 0, 0);
#pragma unroll
                for (int r = 0; r < 16; ++r) {
                    f32x4 uq = (r < 4) ? uu0 : (r < 8) ? uu1 : (r < 12) ? uu2 : uu3;
                    W[r] = d[r] * uq[r & 3];
                }
                if (u == 7) renorm16(W, Sacc);
            }
        }
        {   // tail: rem = 2 (segs 0-6) or 1 (seg 7); slots 0,1 hold steps s, s+1
            const int rem = cnt - s;
            if (lane < 32) {
#pragma unroll
                for (int j = 2; j < 8; ++j)
                    if (j < rem) uring[wid][j][col] = FEXP2(LOG2E_F * er[j]);
            }
#pragma unroll
            for (int u = 0; u < 8; ++u) {
                if (u < rem) {
                    f32x4 uu0 = *(const f32x4*)&uring[wid][u][4 * hi];
                    f32x4 uu1 = *(const f32x4*)&uring[wid][u][8 + 4 * hi];
                    f32x4 uu2 = *(const f32x4*)&uring[wid][u][16 + 4 * hi];
                    f32x4 uu3 = *(const f32x4*)&uring[wid][u][24 + 4 * hi];
                    bf16x8 B1, B2;
                    packDtoB(W, B1, B2);
                    f32x16 d = __builtin_amdgcn_mfma_f32_32x32x16_bf16(A1, B1, z, 0, 0, 0);
                    d = __builtin_amdgcn_mfma_f32_32x32x16_bf16(A2, B2, d, 0, 0, 0);
#pragma unroll
                    for (int r = 0; r < 16; ++r) {
                        f32x4 uq = (r < 4) ? uu0 : (r < 8) ? uu1 : (r < 12) ? uu2 : uu3;
                        W[r] = d[r] * uq[r & 3];
                    }
                }
            }
            renorm16(W, Sacc);
        }

        // store P_w
#pragma unroll
        for (int r = 0; r < 16; ++r) {
            int row = (r & 3) + 8 * (r >> 2) + 4 * hi;
            mats[wid][row][col] = W[r];
        }
        if (lane == 0) scl[wid] = Sacc;
        __syncthreads();

        // LDS matrix pair product: out(D-layout regs) = Lm x Rm
        auto lds_mul = [&](const float (*Lm)[33], const float (*Rm)[33], float* Wo) {
            unsigned lw[8];
#pragma unroll
            for (int p = 0; p < 8; ++p) {
                int kb = (p >> 2) * 16 + 8 * hi + (p & 3) * 2;
                lw[p] = (unsigned)f2bf_rne(Lm[col][kb]) |
                        ((unsigned)f2bf_rne(Lm[col][kb + 1]) << 16);
            }
            bf16x8 LA1 = __builtin_bit_cast(bf16x8, u32x4{lw[0], lw[1], lw[2], lw[3]});
            bf16x8 LA2 = __builtin_bit_cast(bf16x8, u32x4{lw[4], lw[5], lw[6], lw[7]});
            float Wr[16];
#pragma unroll
            for (int r = 0; r < 16; ++r) {
                int row = (r & 3) + 8 * (r >> 2) + 4 * hi;
                Wr[r] = Rm[row][col];
            }
            bf16x8 B1, B2;
            packDtoB(Wr, B1, B2);
            f32x16 d = __builtin_amdgcn_mfma_f32_32x32x16_bf16(LA1, B1, z, 0, 0, 0);
            d = __builtin_amdgcn_mfma_f32_32x32x16_bf16(LA2, B2, d, 0, 0, 0);
#pragma unroll
            for (int r = 0; r < 16; ++r) Wo[r] = d[r];
        };
        auto store_mat = [&](int slot, const float* Wo) {
#pragma unroll
            for (int r = 0; r < 16; ++r) {
                int row = (r & 3) + 8 * (r >> 2) + 4 * hi;
                mats[slot][row][col] = Wo[r];
            }
        };

        // L1: wid<4: mats[2w] <- P_{2w+1} x P_{2w}   (only wave w touches slot 2w)
        if (wid < 4) {
            float Wq[16];
            lds_mul(mats[2 * wid + 1], mats[2 * wid], Wq);
            float Sg = scl[2 * wid] + scl[2 * wid + 1];
            renorm16(Wq, Sg);
            store_mat(2 * wid, Wq);
            if (lane == 0) scl[2 * wid] = Sg;
        }
        __syncthreads();
        // L2: wid<2: mats[4w] <- mats[4w+2] x mats[4w]
        if (wid < 2) {
            float Wq[16];
            lds_mul(mats[4 * wid + 2], mats[4 * wid], Wq);
            float Sg = scl[4 * wid] + scl[4 * wid + 2];
            renorm16(Wq, Sg);
            store_mat(4 * wid, Wq);
            if (lane == 0) scl[4 * wid] = Sg;
        }
        __syncthreads();
        // L3 + alpha0 apply (wave 0): R = mats[4] x mats[0]
        if (wid == 0) {
            float Wq[16];
            lds_mul(mats[4], mats[0], Wq);
            const float Stot = scl[0] + scl[4];
            float a0v = 0.f;
            if (col < Cn)
                a0v = FEXP2(LOG2E_F * (inp[(size_t)b * Cn + col] + tr[col]));
            float ssum = 0.f;
#pragma unroll
            for (int r = 0; r < 16; ++r) ssum += Wq[r];
            float t = ssum * a0v;
#pragma unroll
            for (int sh = 1; sh <= 32; sh <<= 1) t += __shfl_xor(t, sh);
            if (lane == 0) ws[WS_DEN_F + b] = FLOG2(t) + Stot;
        }
    } else {
        // ============ NUMERATOR (round-2 validated form; 8 waves/block) ======
        const int nid = bid * 8 + (tid >> 6);
        const int dir = nid >> 9;
        const int b   = nid & 511;
        const int k   = tid & 63;
        const int* tb = tg + b * Ln;

        const int l0 = 3 * k, l1 = 3 * k + 1, l2 = 3 * k + 2;
        const int t0i = (l0 < Ln) ? tb[l0] : 0;
        const int t1i = (l1 < Ln) ? tb[l1] : 0;
        const int t2i = (l2 < Ln) ? tb[l2] : 0;
        const float s0c = LOG2E_F * tr[(1 + t0i) * Cn + t0i];
        const float s1c = LOG2E_F * tr[(1 + t1i) * Cn + t1i];
        const float s2c = LOG2E_F * tr[(1 + t2i) * Cn + t2i];
        const int   p0  = (l0 >= 1 && l0 < Ln) ? tb[l0 - 1] : 0;
        const float m0c = (l0 >= 1 && l0 < Ln) ? LOG2E_F * tr[(1 + t0i) * Cn + p0] : 0.0f;
        const float m1c = (l1 < Ln) ? LOG2E_F * tr[(1 + t1i) * Cn + t0i] : 0.0f;
        const float m2c = (l2 < Ln) ? LOG2E_F * tr[(1 + t2i) * Cn + t1i] : 0.0f;

        float a0 = NEGV, a1 = NEGV, a2 = NEGV;
        if (dir == 0) {
            if (k == 0) a0 = LOG2E_F * (tr[t0i] + inp[(size_t)b * Cn + t0i]);
        } else {
            if (k == 49) a2 = 0.0f;
        }

        const int kk = (k < Cn) ? k : (Cn - 1);
        const float* eb = inp + (size_t)b * Cn + kk;
        const int t0    = dir ? (Tn - 1) : 1;
        const int dt    = dir ? -1 : 1;
        const int steps = dir ? 1000 : 999;

        float ce[8], ne[8];
#pragma unroll
        for (int u = 0; u < 8; ++u) {
            int tt = t0 + u * dt; tt = max(0, min(Tn - 1, tt));
            ce[u] = LOG2E_F * eb[(size_t)tt * (Bn * Cn)];
        }

        for (int s = 0; s < steps; s += 8) {
#pragma unroll
            for (int u = 0; u < 8; ++u) {
                int tt = t0 + (s + 8 + u) * dt; tt = max(0, min(Tn - 1, tt));
                ne[u] = LOG2E_F * eb[(size_t)tt * (Bn * Cn)];
            }
#pragma unroll
            for (int u = 0; u < 8; ++u) {
                if (s + u < steps) {
                    float rv = ce[u];
                    float e0  = __shfl(rv, t0i);
                    float e1  = __shfl(rv, t1i);
                    float eg2 = __shfl(rv, t2i);
                    if (dir == 0) {
                        float sh = __shfl_up(a2, 1);
                        sh = (k == 0) ? NEGV : sh;
                        float n0 = e0  + ladd2(a0 + s0c, sh + m0c);
                        float n1 = e1  + ladd2(a1 + s1c, a0 + m1c);
                        float n2 = eg2 + ladd2(a2 + s2c, a1 + m2c);
                        a0 = n0; a1 = n1; a2 = n2;
                    } else {
                        float sv0 = a0 + s0c + e0;
                        float mv0 = a0 + m0c + e0;
                        float sv1 = a1 + s1c + e1;
                        float mv1 = a1 + m1c + e1;
                        float sv2 = a2 + s2c + eg2;
                        float mv2 = a2 + m2c + eg2;
                        float mn = __shfl_down(mv0, 1);
                        mn = (k == 49) ? NEGV : mn;
                        a0 = ladd2(sv0, mv1);
                        a1 = ladd2(sv1, mv2);
                        a2 = ladd2(sv2, mn);
                    }
                }
            }
#pragma unroll
            for (int u = 0; u < 8; ++u) ce[u] = ne[u];
        }
        const int base = (dir ? WS_NUM_B : WS_NUM_F) + b * 160;
        if (l0 < Ln)     ws[base + l0]     = a0;
        if (l0 + 1 < Ln) ws[base + l0 + 1] = a1;
        if (l0 + 2 < Ln) ws[base + l0 + 2] = a2;
    }
}

__global__ __launch_bounds__(512)
void asg_combine(const float* __restrict__ ws, float* __restrict__ out)
{
    __shared__ float red[512];
    const int b = threadIdx.x;

    const float ld = ws[WS_DEN_F + b];            // log2 domain

    const float* nf = ws + WS_NUM_F + b * 160;
    const float* nb = ws + WS_NUM_B + b * 160;
    float vm2 = -3.0e38f;
    for (int l = 0; l < Ln; ++l) vm2 = fmaxf(vm2, nf[l] + nb[l]);
    float sum2 = 0.f;
    for (int l = 0; l < Ln; ++l) sum2 += FEXP2(nf[l] + nb[l] - vm2);
    float ln = vm2 + FLOG2(sum2);

    red[b] = ld - ln;
    __syncthreads();
    for (int off = 256; off > 0; off >>= 1) {
        if (b < off) red[b] += red[b + off];
        __syncthreads();
    }
    if (b == 0) out[0] = red[0] * (LN2_F / 512.0f);
}

extern "C" void kernel_launch(void* const* d_in, const int* in_sizes, int n_in,
                              void* d_out, int out_size, void* d_ws, size_t ws_size,
                              hipStream_t stream)
{
    const float* inp = (const float*)d_in[0];
    const float* tr  = (const float*)d_in[1];
    const int*   tg  = (const int*)d_in[2];
    float* out = (float*)d_out;
    float* ws  = (float*)d_ws;

    hipLaunchKernelGGL(asg_scan,    dim3(640), dim3(512), 0, stream, inp, tr, tg, ws);
    hipLaunchKernelGGL(asg_combine, dim3(1),   dim3(512), 0, stream, ws, out);
}

// Round 10
// 253.250 us; speedup vs baseline: 1.1301x; 1.1301x over previous
//
#include <hip/hip_runtime.h>

static constexpr int Tn = 2000;
static constexpr int Bn = 512;
static constexpr int Cn = 29;
static constexpr int Ln = 150;
static constexpr float LOG2E_F = 1.4426950408889634f;
static constexpr float LN2_F   = 0.6931471805599453f;
static constexpr float NEGV    = -1e30f;

// workspace layout (floats)
static constexpr int WS_DEN_F = 0;                      // 512 (log2-domain log_den per b)
static constexpr int WS_NUM_F = 2 * 512 * 32;           // 512*160
static constexpr int WS_NUM_B = 2 * 512 * 32 + 512 * 160;

static constexpr int NSEG = 8;                          // den segments per batch
static constexpr int SEGL = 250;                        // steps per segment (last: 249)

typedef float  f32x16 __attribute__((ext_vector_type(16)));
typedef float  f32x4  __attribute__((ext_vector_type(4)));
typedef __bf16 bf16x8 __attribute__((ext_vector_type(8)));
typedef unsigned int u32x4 __attribute__((ext_vector_type(4)));

#if __has_builtin(__builtin_amdgcn_exp2f)
#define FEXP2(x) __builtin_amdgcn_exp2f(x)
#else
#define FEXP2(x) exp2f(x)
#endif
#if __has_builtin(__builtin_amdgcn_logf)
#define FLOG2(x) __builtin_amdgcn_logf(x)
#else
#define FLOG2(x) log2f(x)
#endif

__device__ __forceinline__ int exp_of(float x) {           // floor(log2(x)), x normal >0
    return ((__float_as_int(x) >> 23) & 255) - 127;
}
__device__ __forceinline__ float pow2i(int e) {            // 2^e, e in [-126,127]
    return __int_as_float((e + 127) << 23);
}
__device__ __forceinline__ unsigned short f2bf_rne(float x) {
    unsigned u = __float_as_uint(x);
    u += 0x7fffu + ((u >> 16) & 1u);
    return (unsigned short)(u >> 16);
}
__device__ __forceinline__ unsigned cvtpk_bf16(float lo, float hi) {
    unsigned r;
    asm("v_cvt_pk_bf16_f32 %0, %1, %2" : "=v"(r) : "v"(lo), "v"(hi));
    return r;
}
__device__ __forceinline__ void xswap32(unsigned &a, unsigned &b) {
#if __has_builtin(__builtin_amdgcn_permlane32_swap)
    auto r = __builtin_amdgcn_permlane32_swap(a, b, false, false);
    a = r[0]; b = r[1];
#else
    unsigned pa = (unsigned)__shfl_xor((int)a, 32);
    unsigned pb = (unsigned)__shfl_xor((int)b, 32);
    bool hb = (threadIdx.x & 32) != 0;
    unsigned na = hb ? pb : a;
    unsigned nb = hb ? b : pa;
    a = na; b = nb;
#endif
}
// D-layout f32[16] -> B-operand fragments (validated r4-r8)
__device__ __forceinline__ void packDtoB(const float* W, bf16x8 &B1, bf16x8 &B2) {
    unsigned pk[8];
#pragma unroll
    for (int q = 0; q < 8; ++q) pk[q] = cvtpk_bf16(W[2 * q], W[2 * q + 1]);
    xswap32(pk[0], pk[2]); xswap32(pk[1], pk[3]);
    xswap32(pk[4], pk[6]); xswap32(pk[5], pk[7]);
    B1 = __builtin_bit_cast(bf16x8, u32x4{pk[0], pk[1], pk[2], pk[3]});
    B2 = __builtin_bit_cast(bf16x8, u32x4{pk[4], pk[5], pk[6], pk[7]});
}
__device__ __forceinline__ void renorm16(float* W, float &Sacc) {
    float m = W[0];
#pragma unroll
    for (int r = 1; r < 16; ++r) m = fmaxf(m, W[r]);
#pragma unroll
    for (int sh = 1; sh <= 32; sh <<= 1) m = fmaxf(m, __shfl_xor(m, sh));
    int g = exp_of(m);
    float iv = pow2i(-g);
#pragma unroll
    for (int r = 0; r < 16; ++r) W[r] *= iv;
    Sacc += (float)g;
}

__global__ __launch_bounds__(512)
void asg_scan(const float* __restrict__ inp, const float* __restrict__ tr,
              const int* __restrict__ tg, float* __restrict__ ws)
{
    const int tid = threadIdx.x;
    const int bid = blockIdx.x;

    __shared__ float mats[NSEG][32][33];
    __shared__ float uring[NSEG][8][32];
    __shared__ float scl[NSEG];

    if (bid >= 128) {
        // ============ DENOMINATOR: 8 segment transfer matrices / batch =======
        // (byte-identical to round-8 validated version)
        const int lane = tid & 63;
        const int wid  = tid >> 6;           // 0..7 = segment
        const int col  = lane & 31;
        const int hi   = lane >> 5;
        const int b    = bid - 128;
        const size_t BC = (size_t)Bn * Cn;

        unsigned aw[8];
#pragma unroll
        for (int p = 0; p < 8; ++p) {
            int kb = (p >> 2) * 16 + 8 * hi + (p & 3) * 2;
            unsigned short lo = 0, hh = 0;
            if (col < Cn) {
                if (kb < Cn)     lo = f2bf_rne(FEXP2(LOG2E_F * tr[(1 + col) * Cn + kb]));
                if (kb + 1 < Cn) hh = f2bf_rne(FEXP2(LOG2E_F * tr[(1 + col) * Cn + kb + 1]));
            }
            aw[p] = (unsigned)lo | ((unsigned)hh << 16);
        }
        const bf16x8 A1 = __builtin_bit_cast(bf16x8, u32x4{aw[0], aw[1], aw[2], aw[3]});
        const bf16x8 A2 = __builtin_bit_cast(bf16x8, u32x4{aw[4], aw[5], aw[6], aw[7]});

        f32x16 z;
#pragma unroll
        for (int r = 0; r < 16; ++r) z[r] = 0.f;

        const int start = 1 + SEGL * wid;
        const int cnt   = min(SEGL, Tn - start);           // 250 ... 249

        const float* ebase = inp + (size_t)b * Cn + min(col, Cn - 1);

        float er[8];
#pragma unroll
        for (int p = 0; p < 8; ++p)
            er[p] = ebase[(size_t)min(start + p, Tn - 1) * BC];

        if (lane < 32) {
            uring[wid][0][col] = FEXP2(LOG2E_F * er[0]);
            uring[wid][1][col] = FEXP2(LOG2E_F * er[1]);
        }

        float W[16];                                       // M in D-layout, init I
#pragma unroll
        for (int r = 0; r < 16; ++r) {
            int row = (r & 3) + 8 * (r >> 2) + 4 * hi;
            W[r] = (row == col) ? 1.0f : 0.0f;
        }
        float Sacc = 0.f;

        int s = 0;
        for (; s + 8 <= cnt; s += 8) {
#pragma unroll
            for (int u = 0; u < 8; ++u) {
                er[u] = ebase[(size_t)min(start + s + u + 8, Tn - 1) * BC];  // prefetch
                float un = FEXP2(LOG2E_F * er[(u + 2) & 7]);                 // step s+u+2
                if (lane < 32) uring[wid][(u + 2) & 7][col] = un;
                f32x4 uu0 = *(const f32x4*)&uring[wid][u][4 * hi];
                f32x4 uu1 = *(const f32x4*)&uring[wid][u][8 + 4 * hi];
                f32x4 uu2 = *(const f32x4*)&uring[wid][u][16 + 4 * hi];
                f32x4 uu3 = *(const f32x4*)&uring[wid][u][24 + 4 * hi];
                bf16x8 B1, B2;
                packDtoB(W, B1, B2);
                f32x16 d = __builtin_amdgcn_mfma_f32_32x32x16_bf16(A1, B1, z, 0, 0, 0);
                d = __builtin_amdgcn_mfma_f32_32x32x16_bf16(A2, B2, d, 0, 0, 0);
#pragma unroll
                for (int r = 0; r < 16; ++r) {
                    f32x4 uq = (r < 4) ? uu0 : (r < 8) ? uu1 : (r < 12) ? uu2 : uu3;
                    W[r] = d[r] * uq[r & 3];
                }
                if (u == 7) renorm16(W, Sacc);
            }
        }
        {   // tail: rem = 2 (segs 0-6) or 1 (seg 7); slots 0,1 hold steps s, s+1
            const int rem = cnt - s;
            if (lane < 32) {
#pragma unroll
                for (int j = 2; j < 8; ++j)
                    if (j < rem) uring[wid][j][col] = FEXP2(LOG2E_F * er[j]);
            }
#pragma unroll
            for (int u = 0; u < 8; ++u) {
                if (u < rem) {
                    f32x4 uu0 = *(const f32x4*)&uring[wid][u][4 * hi];
                    f32x4 uu1 = *(const f32x4*)&uring[wid][u][8 + 4 * hi];
                    f32x4 uu2 = *(const f32x4*)&uring[wid][u][16 + 4 * hi];
                    f32x4 uu3 = *(const f32x4*)&uring[wid][u][24 + 4 * hi];
                    bf16x8 B1, B2;
                    packDtoB(W, B1, B2);
                    f32x16 d = __builtin_amdgcn_mfma_f32_32x32x16_bf16(A1, B1, z, 0, 0, 0);
                    d = __builtin_amdgcn_mfma_f32_32x32x16_bf16(A2, B2, d, 0, 0, 0);
#pragma unroll
                    for (int r = 0; r < 16; ++r) {
                        f32x4 uq = (r < 4) ? uu0 : (r < 8) ? uu1 : (r < 12) ? uu2 : uu3;
                        W[r] = d[r] * uq[r & 3];
                    }
                }
            }
            renorm16(W, Sacc);
        }

#pragma unroll
        for (int r = 0; r < 16; ++r) {
            int row = (r & 3) + 8 * (r >> 2) + 4 * hi;
            mats[wid][row][col] = W[r];
        }
        if (lane == 0) scl[wid] = Sacc;
        __syncthreads();

        auto lds_mul = [&](const float (*Lm)[33], const float (*Rm)[33], float* Wo) {
            unsigned lw[8];
#pragma unroll
            for (int p = 0; p < 8; ++p) {
                int kb = (p >> 2) * 16 + 8 * hi + (p & 3) * 2;
                lw[p] = (unsigned)f2bf_rne(Lm[col][kb]) |
                        ((unsigned)f2bf_rne(Lm[col][kb + 1]) << 16);
            }
            bf16x8 LA1 = __builtin_bit_cast(bf16x8, u32x4{lw[0], lw[1], lw[2], lw[3]});
            bf16x8 LA2 = __builtin_bit_cast(bf16x8, u32x4{lw[4], lw[5], lw[6], lw[7]});
            float Wr[16];
#pragma unroll
            for (int r = 0; r < 16; ++r) {
                int row = (r & 3) + 8 * (r >> 2) + 4 * hi;
                Wr[r] = Rm[row][col];
            }
            bf16x8 B1, B2;
            packDtoB(Wr, B1, B2);
            f32x16 d = __builtin_amdgcn_mfma_f32_32x32x16_bf16(LA1, B1, z, 0, 0, 0);
            d = __builtin_amdgcn_mfma_f32_32x32x16_bf16(LA2, B2, d, 0, 0, 0);
#pragma unroll
            for (int r = 0; r < 16; ++r) Wo[r] = d[r];
        };
        auto store_mat = [&](int slot, const float* Wo) {
#pragma unroll
            for (int r = 0; r < 16; ++r) {
                int row = (r & 3) + 8 * (r >> 2) + 4 * hi;
                mats[slot][row][col] = Wo[r];
            }
        };

        if (wid < 4) {
            float Wq[16];
            lds_mul(mats[2 * wid + 1], mats[2 * wid], Wq);
            float Sg = scl[2 * wid] + scl[2 * wid + 1];
            renorm16(Wq, Sg);
            store_mat(2 * wid, Wq);
            if (lane == 0) scl[2 * wid] = Sg;
        }
        __syncthreads();
        if (wid < 2) {
            float Wq[16];
            lds_mul(mats[4 * wid + 2], mats[4 * wid], Wq);
            float Sg = scl[4 * wid] + scl[4 * wid + 2];
            renorm16(Wq, Sg);
            store_mat(4 * wid, Wq);
            if (lane == 0) scl[4 * wid] = Sg;
        }
        __syncthreads();
        if (wid == 0) {
            float Wq[16];
            lds_mul(mats[4], mats[0], Wq);
            const float Stot = scl[0] + scl[4];
            float a0v = 0.f;
            if (col < Cn)
                a0v = FEXP2(LOG2E_F * (inp[(size_t)b * Cn + col] + tr[col]));
            float ssum = 0.f;
#pragma unroll
            for (int r = 0; r < 16; ++r) ssum += Wq[r];
            float t = ssum * a0v;
#pragma unroll
            for (int sh = 1; sh <= 32; sh <<= 1) t += __shfl_xor(t, sh);
            if (lane == 0) ws[WS_DEN_F + b] = FLOG2(t) + Stot;
        }
    } else {
        // ==== NUMERATOR: linear domain, PER-LANE pow2 scales (r3-validated math,
        //      ldexpf -> pow2i, direct gather loads) ====
        const int nid = bid * 8 + (tid >> 6);
        const int dir = nid >> 9;
        const int b   = nid & 511;
        const int k   = tid & 63;
        const int* tb = tg + b * Ln;

        const int l0 = 3 * k, l1 = 3 * k + 1, l2 = 3 * k + 2;
        const int t0i = (l0 < Ln) ? tb[l0] : 0;
        const int t1i = (l1 < Ln) ? tb[l1] : 0;
        const int t2i = (l2 < Ln) ? tb[l2] : 0;
        const float S0 = FEXP2(LOG2E_F * tr[(1 + t0i) * Cn + t0i]);
        const float S1 = FEXP2(LOG2E_F * tr[(1 + t1i) * Cn + t1i]);
        const float S2 = FEXP2(LOG2E_F * tr[(1 + t2i) * Cn + t2i]);
        const float M0 = (l0 >= 1 && l0 < Ln)
                         ? FEXP2(LOG2E_F * tr[(1 + t0i) * Cn + tb[l0 - 1]]) : 0.f;
        const float M1 = (l1 < Ln) ? FEXP2(LOG2E_F * tr[(1 + t1i) * Cn + t0i]) : 0.f;
        const float M2 = (l2 < Ln) ? FEXP2(LOG2E_F * tr[(1 + t2i) * Cn + t1i]) : 0.f;

        float w0 = 0.f, w1 = 0.f, w2 = 0.f;
        if (dir == 0) {
            if (k == 0) w0 = FEXP2(LOG2E_F * (tr[t0i] + inp[(size_t)b * Cn + t0i]));
        } else {
            if (k == 49) w2 = 1.f;    // beta_{T-1}[L-1] = 1 (linear)
        }
        int   sE  = 0;                // per-lane scale exponent (log2)
        float m0x = M0;               // fwd: M0 * 2^(s_{k-1}-s_k)
        float fdn = 1.f;              // bwd: 2^(s_{k+1}-s_k)
        int   pgx = 0, psp = 0;       // pending renorm; neighbor prospective scale

        const size_t BC = (size_t)Bn * Cn;
        const int o0 = b * Cn + t0i, o1 = b * Cn + t1i, o2 = b * Cn + t2i;
        const int t0 = dir ? (Tn - 1) : 1;
        const int dt = dir ? -1 : 1;
        const int steps = dir ? 1000 : 999;

        float ue0[4], ue1[4], ue2[4], nr0[4], nr1[4], nr2[4];
#pragma unroll
        for (int u = 0; u < 4; ++u) {          // prime block 0 (converted)
            const float* pt = inp + (size_t)(t0 + u * dt) * BC;
            ue0[u] = FEXP2(LOG2E_F * pt[o0]);
            ue1[u] = FEXP2(LOG2E_F * pt[o1]);
            ue2[u] = FEXP2(LOG2E_F * pt[o2]);
        }

        for (int s = 0; s < steps; s += 4) {
#pragma unroll
            for (int u = 0; u < 4; ++u) {      // load block s+4 (always in range)
                const float* pt = inp + (size_t)(t0 + (s + 4 + u) * dt) * BC;
                nr0[u] = pt[o0]; nr1[u] = pt[o1]; nr2[u] = pt[o2];
            }
#pragma unroll
            for (int u = 0; u < 4; ++u) {
                if (s + u < steps) {
                    if (u == 1) {              // apply pending renorm (measured @u==3)
                        float rs = pow2i(-pgx);
                        w0 *= rs; w1 *= rs; w2 *= rs; sE += pgx;
                        int df = psp - sE;
                        df = max(-126, min(56, df));
                        float fx = pow2i(df);
                        m0x = M0 * fx; fdn = fx;
                    }
                    if (dir == 0) {
                        float sh = __shfl_up(w2, 1);
                        sh = (k == 0) ? 0.f : sh;
                        float n0 = ue0[u] * fmaf(w0, S0, sh * m0x);
                        float n1 = ue1[u] * fmaf(w1, S1, w0 * M1);
                        float n2 = ue2[u] * fmaf(w2, S2, w1 * M2);
                        w0 = n0; w1 = n1; w2 = n2;
                    } else {
                        float q0 = w0 * ue0[u], q1 = w1 * ue1[u], q2 = w2 * ue2[u];
                        float mn = __shfl_down(q0 * M0, 1);   // lane 50 sends 0
                        w0 = fmaf(q0, S0, q1 * M1);
                        w1 = fmaf(q1, S1, q2 * M2);
                        w2 = fmaf(q2, S2, mn * fdn);
                    }
                    if (u == 3) {              // measure renorm + neighbor scale
                        float mxn = fmaxf(fmaxf(w0, w1), w2);
                        pgx = (mxn > 0.f) ? exp_of(mxn) : 0;
                        int sp = sE + pgx;
                        psp = dir ? __shfl_down(sp, 1) : __shfl_up(sp, 1);
                    }
                }
            }
#pragma unroll
            for (int u = 0; u < 4; ++u) {      // convert next block (off chain)
                ue0[u] = FEXP2(LOG2E_F * nr0[u]);
                ue1[u] = FEXP2(LOG2E_F * nr1[u]);
                ue2[u] = FEXP2(LOG2E_F * nr2[u]);
            }
        }
        const float fsE = (float)sE;
        const int base = (dir ? WS_NUM_B : WS_NUM_F) + b * 160;
        if (l0 < Ln)     ws[base + l0]     = (w0 > 0.f) ? FLOG2(w0) + fsE : NEGV;
        if (l0 + 1 < Ln) ws[base + l0 + 1] = (w1 > 0.f) ? FLOG2(w1) + fsE : NEGV;
        if (l0 + 2 < Ln) ws[base + l0 + 2] = (w2 > 0.f) ? FLOG2(w2) + fsE : NEGV;
    }
}

__global__ __launch_bounds__(512)
void asg_combine(const float* __restrict__ ws, float* __restrict__ out)
{
    __shared__ float red[512];
    const int b = threadIdx.x;

    const float ld = ws[WS_DEN_F + b];            // log2 domain

    const float* nf = ws + WS_NUM_F + b * 160;
    const float* nb = ws + WS_NUM_B + b * 160;
    float vm2 = -3.0e38f;
    for (int l = 0; l < Ln; ++l) vm2 = fmaxf(vm2, nf[l] + nb[l]);
    float sum2 = 0.f;
    for (int l = 0; l < Ln; ++l) sum2 += FEXP2(nf[l] + nb[l] - vm2);
    float ln = vm2 + FLOG2(sum2);

    red[b] = ld - ln;
    __syncthreads();
    for (int off = 256; off > 0; off >>= 1) {
        if (b < off) red[b] += red[b + off];
        __syncthreads();
    }
    if (b == 0) out[0] = red[0] * (LN2_F / 512.0f);
}

extern "C" void kernel_launch(void* const* d_in, const int* in_sizes, int n_in,
                              void* d_out, int out_size, void* d_ws, size_t ws_size,
                              hipStream_t stream)
{
    const float* inp = (const float*)d_in[0];
    const float* tr  = (const float*)d_in[1];
    const int*   tg  = (const int*)d_in[2];
    float* out = (float*)d_out;
    float* ws  = (float*)d_ws;

    hipLaunchKernelGGL(asg_scan,    dim3(640), dim3(512), 0, stream, inp, tr, tg, ws);
    hipLaunchKernelGGL(asg_combine, dim3(1),   dim3(512), 0, stream, ws, out);
}